// Round 1
// baseline (198.338 us; speedup 1.0000x reference)
//
#include <hip/hip_runtime.h>
#include <hip/hip_bf16.h>

// Problem constants (from reference)
#define M_TOTAL 131072
#define K_DIM   512
#define N_RANK  256
#define NSEG    1024

typedef __attribute__((ext_vector_type(8))) short bf16x8;
typedef __attribute__((ext_vector_type(4))) float f32x4;

__device__ inline short f2b(float f) {
    __hip_bfloat16 h = __float2bfloat16(f);
    return __builtin_bit_cast(short, h);
}

// CAS-based atomic multiply (device scope, cross-XCD safe)
__device__ inline void atomicMulF(float* p, float v) {
    unsigned int* ip = reinterpret_cast<unsigned int*>(p);
    unsigned int old = *ip;
    unsigned int assumed;
    do {
        assumed = old;
        float nv = __uint_as_float(assumed) * v;
        old = atomicCAS(ip, assumed, __float_as_uint(nv));
    } while (old != assumed);
}

// fast tanh: t = sign(z) * (1 - 2/(e^{2|z|}+1)); __expf(inf-range) -> inf -> t=±1
__device__ inline float fast_tanh(float z) {
    float e = __expf(2.0f * fabsf(z));
    return copysignf(1.0f - 2.0f / (e + 1.0f), z);
}

// Kernel 1: init out to 1.0 (segment_prod identity) + convert W to bf16 in ws
__global__ void prep_kernel(const float* __restrict__ W,
                            __hip_bfloat16* __restrict__ Wb,
                            float* __restrict__ out) {
    int i = blockIdx.x * 256 + threadIdx.x;      // grid 1024 -> 262144 threads
    out[i] = 1.0f;                               // all NSEG*N_RANK elements
    if (i < N_RANK * K_DIM) Wb[i] = __float2bfloat16(W[i]);
}

// Kernel 2: fused GEMM(bf16 MFMA) + bias + tanh + segmented product
// Block: 256 threads (4 waves). Each block owns 64 rows of x, full 256 cols.
// Wave w computes 64 rows x cols [w*64, w*64+64).
__launch_bounds__(256, 3)
__global__ void fused_kernel(const float* __restrict__ x,
                             const __hip_bfloat16* __restrict__ Wb,
                             const float* __restrict__ bias,
                             const int* __restrict__ seg,
                             float* __restrict__ out) {
    const int tid  = threadIdx.x;
    const int wave = tid >> 6;       // 0..3
    const int lane = tid & 63;
    const int l16  = lane & 15;
    const int g    = lane >> 4;      // 0..3 (k-group)
    const int m0   = blockIdx.x * 64;
    const int n0   = wave * 64;

    f32x4 acc[4][4] = {};            // [m-frag][n-frag], 64 f32

    // ---- K loop: 16 steps of K=32 ----
    for (int k0 = 0; k0 < K_DIM; k0 += 32) {
        const int kk = k0 + g * 8;

        bf16x8 a[4];
        #pragma unroll
        for (int i = 0; i < 4; ++i) {
            const float* xp = x + (size_t)(m0 + i * 16 + l16) * K_DIM + kk;
            f32x4 lo = *reinterpret_cast<const f32x4*>(xp);
            f32x4 hi = *reinterpret_cast<const f32x4*>(xp + 4);
            bf16x8 av;
            av[0] = f2b(lo[0]); av[1] = f2b(lo[1]);
            av[2] = f2b(lo[2]); av[3] = f2b(lo[3]);
            av[4] = f2b(hi[0]); av[5] = f2b(hi[1]);
            av[6] = f2b(hi[2]); av[7] = f2b(hi[3]);
            a[i] = av;
        }

        bf16x8 bfr[4];
        #pragma unroll
        for (int j = 0; j < 4; ++j) {
            const __hip_bfloat16* wp = Wb + (size_t)(n0 + j * 16 + l16) * K_DIM + kk;
            bfr[j] = *reinterpret_cast<const bf16x8*>(wp);
        }

        #pragma unroll
        for (int i = 0; i < 4; ++i)
            #pragma unroll
            for (int j = 0; j < 4; ++j)
                acc[i][j] = __builtin_amdgcn_mfma_f32_16x16x32_bf16(a[i], bfr[j], acc[i][j], 0, 0, 0);
    }

    // ---- epilogue: bias + tanh in regs ----
    // D layout (verified m89): col = lane&15, row(within 16x16) = (lane>>4)*4 + r
    #pragma unroll
    for (int j = 0; j < 4; ++j) {
        const float bj = bias[n0 + j * 16 + l16];
        #pragma unroll
        for (int i = 0; i < 4; ++i) {
            #pragma unroll
            for (int r = 0; r < 4; ++r)
                acc[i][j][r] = fast_tanh(acc[i][j][r] + bj);
        }
    }

    // ---- segmented product over the block's 64 rows ----
    __shared__ float tl[32 * 258];   // 32 rows staged at a time, stride 258 (conflict-free)
    __shared__ int   segs[64];

    if (tid < 64) segs[tid] = seg[m0 + tid];
    __syncthreads();

    int   cur  = segs[0];
    float prod = 1.0f;
    const int col = tid;             // 0..255, one column per thread

    #pragma unroll
    for (int h = 0; h < 2; ++h) {
        // stage rows [h*32, h*32+32) : m-frags i = 2h, 2h+1
        #pragma unroll
        for (int i2 = 0; i2 < 2; ++i2) {
            const int i = h * 2 + i2;
            #pragma unroll
            for (int j = 0; j < 4; ++j) {
                const int c = n0 + j * 16 + l16;
                #pragma unroll
                for (int r = 0; r < 4; ++r) {
                    const int row = i2 * 16 + g * 4 + r;   // row within half
                    tl[row * 258 + c] = acc[i][j][r];
                }
            }
        }
        __syncthreads();

        // walk 32 rows; segment ids are sorted, branch is block-uniform
        for (int r = 0; r < 32; ++r) {
            const int s = segs[h * 32 + r];
            if (s != cur) {
                atomicMulF(&out[(size_t)cur * N_RANK + col], prod);
                prod = 1.0f;
                cur  = s;
            }
            prod *= tl[r * 258 + col];
        }
        __syncthreads();   // walk done before next half restages
    }
    atomicMulF(&out[(size_t)cur * N_RANK + col], prod);
}

extern "C" void kernel_launch(void* const* d_in, const int* in_sizes, int n_in,
                              void* d_out, int out_size, void* d_ws, size_t ws_size,
                              hipStream_t stream) {
    const float* x   = (const float*)d_in[0];
    const float* W   = (const float*)d_in[1];
    const float* b   = (const float*)d_in[2];
    const int*   seg = (const int*)d_in[3];
    float*       out = (float*)d_out;
    __hip_bfloat16* Wb = (__hip_bfloat16*)d_ws;   // 256 KB of ws

    prep_kernel<<<(NSEG * N_RANK) / 256, 256, 0, stream>>>(W, Wb, out);
    fused_kernel<<<M_TOTAL / 64, 256, 0, stream>>>(x, Wb, b, seg, out);
}

// Round 2
// 118.788 us; speedup vs baseline: 1.6697x; 1.6697x over previous
//
#include <hip/hip_runtime.h>
#include <hip/hip_bf16.h>

// Problem constants (from reference)
#define M_TOTAL 131072
#define K_DIM   512
#define N_RANK  256
#define NSEG    1024
#define KC      64            // k-chunk staged in LDS
#define NKC     (K_DIM / KC)  // 8

typedef __attribute__((ext_vector_type(8))) short bf16x8;
typedef __attribute__((ext_vector_type(4))) float f32x4;

__device__ inline short f2b(float f) {
    __hip_bfloat16 h = __float2bfloat16(f);
    return __builtin_bit_cast(short, h);
}

// CAS-based atomic multiply (device scope, cross-XCD safe)
__device__ inline void atomicMulF(float* p, float v) {
    unsigned int* ip = reinterpret_cast<unsigned int*>(p);
    unsigned int old = *ip;
    unsigned int assumed;
    do {
        assumed = old;
        float nv = __uint_as_float(assumed) * v;
        old = atomicCAS(ip, assumed, __float_as_uint(nv));
    } while (old != assumed);
}

// fast tanh: t = sign(z) * (1 - 2/(e^{2|z|}+1))
__device__ inline float fast_tanh(float z) {
    float e = __expf(2.0f * fabsf(z));
    return copysignf(1.0f - 2.0f / (e + 1.0f), z);
}

// Kernel 1: init out to 1.0 (segment_prod identity) + convert W to bf16 in ws
__global__ void prep_kernel(const float* __restrict__ W,
                            __hip_bfloat16* __restrict__ Wb,
                            float* __restrict__ out) {
    int i = blockIdx.x * 256 + threadIdx.x;
    out[i] = 1.0f;
    if (i < N_RANK * K_DIM) Wb[i] = __float2bfloat16(W[i]);
}

// Kernel 2: fused GEMM(bf16 MFMA, LDS-staged A) + bias + tanh + segmented product
// Block: 256 threads (4 waves). Block owns 64 rows of x, full 256 cols.
// Wave w computes 64 rows x cols [w*64, w*64+64).
// A-tile: 64x64 bf16 in LDS, double-buffered, XOR-swizzled (byte ^= (row&7)<<4).
__launch_bounds__(256, 3)
__global__ void fused_kernel(const float* __restrict__ x,
                             const __hip_bfloat16* __restrict__ Wb,
                             const float* __restrict__ bias,
                             const int* __restrict__ seg,
                             float* __restrict__ out) {
    const int tid  = threadIdx.x;
    const int wave = tid >> 6;
    const int lane = tid & 63;
    const int l16  = lane & 15;
    const int g    = lane >> 4;       // 0..3 (k-group)
    const int m0   = blockIdx.x * 64;
    const int n0   = wave * 64;

    // LDS: A double-buffer (2 x 64 x 64 bf16 = 16 KB) aliased with the
    // epilogue staging buffer tl (32*258 f32 = 33024 B). All A reads complete
    // before the last __syncthreads() of the K loop, so aliasing is safe.
    __shared__ alignas(16) char smem[32 * 258 * 4];
    short* Ab = reinterpret_cast<short*>(smem);
    float* tl = reinterpret_cast<float*>(smem);
    __shared__ int segs[64];

    if (tid < 64) segs[tid] = seg[m0 + tid];

    // staging geometry: thread t covers row (t>>4)+i*16, f32 cols (t&15)*4..+3
    const int srow = tid >> 4;        // 0..15
    const int scol = (tid & 15) * 4;  // f32 element col within chunk
    const int swb  = (tid & 15) * 8;  // byte col within 128-B bf16 row

    f32x4 acc[4][4] = {};             // [m-frag][n-frag]

    // ---- prologue: stage chunk 0 into buf 0 ----
    {
        f32x4 v[4];
        #pragma unroll
        for (int i = 0; i < 4; ++i)
            v[i] = *reinterpret_cast<const f32x4*>(
                x + (size_t)(m0 + srow + i * 16) * K_DIM + scol);
        #pragma unroll
        for (int i = 0; i < 4; ++i) {
            const int row  = srow + i * 16;
            const int byte = row * 128 + (swb ^ ((row & 7) << 4));
            short4 p;
            p.x = f2b(v[i][0]); p.y = f2b(v[i][1]);
            p.z = f2b(v[i][2]); p.w = f2b(v[i][3]);
            *reinterpret_cast<short4*>(smem + byte) = p;
        }
    }
    __syncthreads();

    // ---- K loop: 8 chunks of 64, double-buffered ----
    int cur = 0;
    for (int kc = 0; kc < NKC; ++kc) {
        // B fragments for this chunk (global; L2-resident 256 KB). Issued
        // FIRST so the MFMA's vmcnt wait does not drain the A-prefetch.
        bf16x8 bfr[2][4];
        #pragma unroll
        for (int s = 0; s < 2; ++s)
            #pragma unroll
            for (int j = 0; j < 4; ++j)
                bfr[s][j] = *reinterpret_cast<const bf16x8*>(
                    Wb + (size_t)(n0 + j * 16 + l16) * K_DIM + kc * KC + s * 32 + g * 8);

        // prefetch next A chunk (global -> regs), in flight across the MFMAs
        f32x4 v[4];
        if (kc + 1 < NKC) {
            #pragma unroll
            for (int i = 0; i < 4; ++i)
                v[i] = *reinterpret_cast<const f32x4*>(
                    x + (size_t)(m0 + srow + i * 16) * K_DIM + (kc + 1) * KC + scol);
        }

        // compute from LDS buf[cur]
        #pragma unroll
        for (int s = 0; s < 2; ++s) {
            bf16x8 afr[4];
            #pragma unroll
            for (int i = 0; i < 4; ++i) {
                const int row  = i * 16 + l16;
                const int byte = cur * 8192 + row * 128 +
                                 ((s * 64 + g * 16) ^ ((row & 7) << 4));
                afr[i] = *reinterpret_cast<const bf16x8*>(smem + byte);
            }
            #pragma unroll
            for (int i = 0; i < 4; ++i)
                #pragma unroll
                for (int j = 0; j < 4; ++j)
                    acc[i][j] = __builtin_amdgcn_mfma_f32_16x16x32_bf16(
                        afr[i], bfr[s][j], acc[i][j], 0, 0, 0);
        }

        // convert + write prefetched chunk into the other buffer
        if (kc + 1 < NKC) {
            #pragma unroll
            for (int i = 0; i < 4; ++i) {
                const int row  = srow + i * 16;
                const int byte = (cur ^ 1) * 8192 + row * 128 + (swb ^ ((row & 7) << 4));
                short4 p;
                p.x = f2b(v[i][0]); p.y = f2b(v[i][1]);
                p.z = f2b(v[i][2]); p.w = f2b(v[i][3]);
                *reinterpret_cast<short4*>(smem + byte) = p;
            }
        }
        __syncthreads();
        cur ^= 1;
    }

    // ---- epilogue: bias + tanh in regs ----
    // D layout: col = lane&15, row(within 16x16) = (lane>>4)*4 + r
    #pragma unroll
    for (int j = 0; j < 4; ++j) {
        const float bj = bias[n0 + j * 16 + l16];
        #pragma unroll
        for (int i = 0; i < 4; ++i)
            #pragma unroll
            for (int r = 0; r < 4; ++r)
                acc[i][j][r] = fast_tanh(acc[i][j][r] + bj);
    }

    // ---- segmented product over the block's 64 rows ----
    // (smem now reused as tl[32][258]; all Ab reads drained at last barrier)
    int   curSeg = segs[0];
    float prod   = 1.0f;
    const int col = tid;              // one column per thread

    #pragma unroll
    for (int h = 0; h < 2; ++h) {
        __syncthreads();              // previous phase (K-loop or walk) done
        #pragma unroll
        for (int i2 = 0; i2 < 2; ++i2) {
            const int i = h * 2 + i2;
            #pragma unroll
            for (int j = 0; j < 4; ++j) {
                const int c = n0 + j * 16 + l16;
                #pragma unroll
                for (int r = 0; r < 4; ++r) {
                    const int row = i2 * 16 + g * 4 + r;  // row within half
                    tl[row * 258 + c] = acc[i][j][r];
                }
            }
        }
        __syncthreads();

        for (int r = 0; r < 32; ++r) {
            const int s = segs[h * 32 + r];
            if (s != curSeg) {
                atomicMulF(&out[(size_t)curSeg * N_RANK + col], prod);
                prod   = 1.0f;
                curSeg = s;
            }
            prod *= tl[r * 258 + col];
        }
    }
    atomicMulF(&out[(size_t)curSeg * N_RANK + col], prod);
}

extern "C" void kernel_launch(void* const* d_in, const int* in_sizes, int n_in,
                              void* d_out, int out_size, void* d_ws, size_t ws_size,
                              hipStream_t stream) {
    const float* x   = (const float*)d_in[0];
    const float* W   = (const float*)d_in[1];
    const float* b   = (const float*)d_in[2];
    const int*   seg = (const int*)d_in[3];
    float*       out = (float*)d_out;
    __hip_bfloat16* Wb = (__hip_bfloat16*)d_ws;

    prep_kernel<<<(NSEG * N_RANK) / 256, 256, 0, stream>>>(W, Wb, out);
    fused_kernel<<<M_TOTAL / 64, 256, 0, stream>>>(x, Wb, b, seg, out);
}

// Round 3
// 111.587 us; speedup vs baseline: 1.7774x; 1.0645x over previous
//
#include <hip/hip_runtime.h>
#include <hip/hip_bf16.h>

// Problem constants (from reference)
#define M_TOTAL 131072
#define K_DIM   512
#define N_RANK  256
#define NSEG    1024
#define KC      64            // k-chunk staged in LDS
#define NKC     (K_DIM / KC)  // 8

typedef __attribute__((ext_vector_type(8))) short bf16x8;
typedef __attribute__((ext_vector_type(4))) float f32x4;

__device__ inline short f2b(float f) {
    __hip_bfloat16 h = __float2bfloat16(f);
    return __builtin_bit_cast(short, h);
}

// CAS-based atomic multiply (device scope, cross-XCD safe)
__device__ inline void atomicMulF(float* p, float v) {
    unsigned int* ip = reinterpret_cast<unsigned int*>(p);
    unsigned int old = *ip;
    unsigned int assumed;
    do {
        assumed = old;
        float nv = __uint_as_float(assumed) * v;
        old = atomicCAS(ip, assumed, __float_as_uint(nv));
    } while (old != assumed);
}

// fast tanh: t = sign(z) * (1 - 2/(e^{2|z|}+1))
__device__ inline float fast_tanh(float z) {
    float e = __expf(2.0f * fabsf(z));
    return copysignf(1.0f - 2.0f / (e + 1.0f), z);
}

// Kernel 1: init out to 1.0 (segment_prod identity) + convert W to bf16 in ws
__global__ void prep_kernel(const float* __restrict__ W,
                            __hip_bfloat16* __restrict__ Wb,
                            float* __restrict__ out) {
    int i = blockIdx.x * 256 + threadIdx.x;
    out[i] = 1.0f;
    if (i < N_RANK * K_DIM) Wb[i] = __float2bfloat16(W[i]);
}

// Kernel 2: fused GEMM(bf16 MFMA, LDS-staged A, depth-2 prefetch)
//           + bias + tanh + segmented product
// Block: 256 threads (4 waves). Block owns 64 rows of x, full 256 cols.
// Wave w computes 64 rows x cols [w*64, w*64+64).
// A-tile: 64x64 bf16 in LDS, double-buffered, XOR-swizzled (byte ^= (row&7)<<4).
// Pipeline: at iter kc -- issue B(kc) [L2], issue A(kc+2) [HBM],
//           cvt+write A(kc+1) (its loads are a full iteration old -> no stall),
//           ds_read + MFMA chunk kc.
__launch_bounds__(256, 3)
__global__ void fused_kernel(const float* __restrict__ x,
                             const __hip_bfloat16* __restrict__ Wb,
                             const float* __restrict__ bias,
                             const int* __restrict__ seg,
                             float* __restrict__ out) {
    const int tid  = threadIdx.x;
    const int wave = tid >> 6;
    const int lane = tid & 63;
    const int l16  = lane & 15;
    const int g    = lane >> 4;       // 0..3 (k-group)
    const int m0   = blockIdx.x * 64;
    const int n0   = wave * 64;

    // LDS: A double-buffer (2 x 64 x 64 bf16 = 16 KB) aliased with the
    // epilogue staging buffer tl (32*258 f32 = 33024 B).
    __shared__ alignas(16) char smem[32 * 258 * 4];
    float* tl = reinterpret_cast<float*>(smem);
    __shared__ int segs[64];

    if (tid < 64) segs[tid] = seg[m0 + tid];

    // staging geometry: thread t covers row (t>>4)+i*16, f32 cols (t&15)*4..+3
    const int srow = tid >> 4;        // 0..15
    const int scol = (tid & 15) * 4;  // f32 element col within chunk
    const int swb  = (tid & 15) * 8;  // byte col within 128-B bf16 row

    f32x4 acc[4][4] = {};             // [m-frag][n-frag]
    f32x4 ra[2][4];                   // A prefetch regs, 2 chunks deep

    // ---- prologue: issue chunk0 + chunk1, stage chunk0 into LDS buf 0 ----
    #pragma unroll
    for (int i = 0; i < 4; ++i)
        ra[0][i] = *reinterpret_cast<const f32x4*>(
            x + (size_t)(m0 + srow + i * 16) * K_DIM + scol);
    #pragma unroll
    for (int i = 0; i < 4; ++i)
        ra[1][i] = *reinterpret_cast<const f32x4*>(
            x + (size_t)(m0 + srow + i * 16) * K_DIM + KC + scol);
    #pragma unroll
    for (int i = 0; i < 4; ++i) {
        const int row  = srow + i * 16;
        const int byte = row * 128 + (swb ^ ((row & 7) << 4));
        short4 p;
        p.x = f2b(ra[0][i][0]); p.y = f2b(ra[0][i][1]);
        p.z = f2b(ra[0][i][2]); p.w = f2b(ra[0][i][3]);
        *reinterpret_cast<short4*>(smem + byte) = p;
    }

    // ---- K loop: 8 chunks of 64, depth-2 pipelined, fully unrolled ----
    #pragma unroll
    for (int kc = 0; kc < NKC; ++kc) {
        __syncthreads();   // chunk kc's LDS writes visible; buf (kc+1)&1 free

        // 1) B fragments for this chunk (L2-resident). Issued FIRST so the
        //    MFMA's vmcnt wait for B leaves the newer A-loads in flight.
        bf16x8 bfr[2][4];
        #pragma unroll
        for (int s = 0; s < 2; ++s)
            #pragma unroll
            for (int j = 0; j < 4; ++j)
                bfr[s][j] = *reinterpret_cast<const bf16x8*>(
                    Wb + (size_t)(n0 + j * 16 + l16) * K_DIM + kc * KC + s * 32 + g * 8);

        // 2) issue A loads for chunk kc+2 into slot kc&1 (freed last iter)
        if (kc + 2 < NKC) {
            #pragma unroll
            for (int i = 0; i < 4; ++i)
                ra[kc & 1][i] = *reinterpret_cast<const f32x4*>(
                    x + (size_t)(m0 + srow + i * 16) * K_DIM + (kc + 2) * KC + scol);
        }

        // 3) cvt + write chunk kc+1 (loads issued a full iteration ago)
        if (kc + 1 < NKC) {
            #pragma unroll
            for (int i = 0; i < 4; ++i) {
                const int row  = srow + i * 16;
                const int byte = ((kc + 1) & 1) * 8192 + row * 128 + (swb ^ ((row & 7) << 4));
                short4 p;
                p.x = f2b(ra[(kc + 1) & 1][i][0]); p.y = f2b(ra[(kc + 1) & 1][i][1]);
                p.z = f2b(ra[(kc + 1) & 1][i][2]); p.w = f2b(ra[(kc + 1) & 1][i][3]);
                *reinterpret_cast<short4*>(smem + byte) = p;
            }
        }

        // 4) compute chunk kc from LDS buf kc&1
        #pragma unroll
        for (int s = 0; s < 2; ++s) {
            bf16x8 afr[4];
            #pragma unroll
            for (int i = 0; i < 4; ++i) {
                const int row  = i * 16 + l16;
                const int byte = (kc & 1) * 8192 + row * 128 +
                                 ((s * 64 + g * 16) ^ ((row & 7) << 4));
                afr[i] = *reinterpret_cast<const bf16x8*>(smem + byte);
            }
            #pragma unroll
            for (int i = 0; i < 4; ++i)
                #pragma unroll
                for (int j = 0; j < 4; ++j)
                    acc[i][j] = __builtin_amdgcn_mfma_f32_16x16x32_bf16(
                        afr[i], bfr[s][j], acc[i][j], 0, 0, 0);
        }
    }

    // ---- epilogue: bias + tanh in regs ----
    // D layout: col = lane&15, row(within 16x16) = (lane>>4)*4 + r
    #pragma unroll
    for (int j = 0; j < 4; ++j) {
        const float bj = bias[n0 + j * 16 + l16];
        #pragma unroll
        for (int i = 0; i < 4; ++i)
            #pragma unroll
            for (int r = 0; r < 4; ++r)
                acc[i][j][r] = fast_tanh(acc[i][j][r] + bj);
    }

    // ---- segmented product over the block's 64 rows ----
    int   curSeg = segs[0];
    float prod   = 1.0f;
    const int col = tid;              // one column per thread

    #pragma unroll
    for (int h = 0; h < 2; ++h) {
        __syncthreads();              // previous phase (K-loop or walk) done
        #pragma unroll
        for (int i2 = 0; i2 < 2; ++i2) {
            const int i = h * 2 + i2;
            #pragma unroll
            for (int j = 0; j < 4; ++j) {
                const int c = n0 + j * 16 + l16;
                #pragma unroll
                for (int r = 0; r < 4; ++r) {
                    const int row = i2 * 16 + g * 4 + r;  // row within half
                    tl[row * 258 + c] = acc[i][j][r];
                }
            }
        }
        __syncthreads();

        for (int r = 0; r < 32; ++r) {
            const int s = segs[h * 32 + r];
            if (s != curSeg) {
                atomicMulF(&out[(size_t)curSeg * N_RANK + col], prod);
                prod   = 1.0f;
                curSeg = s;
            }
            prod *= tl[r * 258 + col];
        }
    }
    atomicMulF(&out[(size_t)curSeg * N_RANK + col], prod);
}

extern "C" void kernel_launch(void* const* d_in, const int* in_sizes, int n_in,
                              void* d_out, int out_size, void* d_ws, size_t ws_size,
                              hipStream_t stream) {
    const float* x   = (const float*)d_in[0];
    const float* W   = (const float*)d_in[1];
    const float* b   = (const float*)d_in[2];
    const int*   seg = (const int*)d_in[3];
    float*       out = (float*)d_out;
    __hip_bfloat16* Wb = (__hip_bfloat16*)d_ws;

    prep_kernel<<<(NSEG * N_RANK) / 256, 256, 0, stream>>>(W, Wb, out);
    fused_kernel<<<M_TOTAL / 64, 256, 0, stream>>>(x, Wb, b, seg, out);
}